// Round 5
// baseline (2751.542 us; speedup 1.0000x reference)
//
#include <hip/hip_runtime.h>

// InjectionLayer: event proj + GCNConv diffusion + gated fuse.
// N=100000, E=1600000, EVENT_DIM=64, HID=128.
// Runtime-detects BOTH edge-index width (int32 vs int64) and float dtype
// (float32 vs packed bf16) from device memory; all global loads/stores of
// problem tensors go through dtype-flexible helpers. Internal staging of x is
// always packed bf16 in d_out (dead until final kernel overwrites d_out).

typedef unsigned short inj_u16;
typedef unsigned int   inj_u32;

static constexpr int INJ_N  = 100000;
static constexpr int INJ_E  = 1600000;
static constexpr int INJ_H  = 128;
static constexpr int INJ_D  = 64;
static constexpr int INJ_NB = 16;   // nodes per block in GEMM kernels

__device__ __forceinline__ float inj_b2f(inj_u16 h){
  union { inj_u32 u; float f; } c; c.u = ((inj_u32)h) << 16; return c.f;
}
__device__ __forceinline__ inj_u16 inj_f2b(float x){
  union { inj_u32 u; float f; } c; c.f = x;
  return (inj_u16)((c.u + 0x7FFFu + ((c.u >> 16) & 1u)) >> 16);
}
// dtype-flexible element access: f32 ? float data : packed bf16 data
__device__ __forceinline__ float inj_ld1(const void* p, size_t i, int f32){
  return f32 ? ((const float*)p)[i] : inj_b2f(((const inj_u16*)p)[i]);
}
__device__ __forceinline__ float2 inj_ld2(const void* p, size_t pair, int f32){
  if (f32) return ((const float2*)p)[pair];
  inj_u32 w = ((const inj_u32*)p)[pair];
  float2 r; r.x = inj_b2f((inj_u16)(w & 0xFFFFu)); r.y = inj_b2f((inj_u16)(w >> 16));
  return r;
}
__device__ __forceinline__ void inj_st2(void* p, size_t pair, float a, float b, int f32){
  if (f32){ float2 v; v.x = a; v.y = b; ((float2*)p)[pair] = v; }
  else ((inj_u32*)p)[pair] = ((inj_u32)inj_f2b(b) << 16) | (inj_u32)inj_f2b(a);
}

// ---- runtime format probes ----
// flags[0]: edge_index is int64 (LE, <2^31 => odd 32b words all zero)
// flags[1]: float tensors are float32 (1) vs packed bf16 (0). For bf16 N(0,1)
// data, bits 14:7 of the low u16 of each u32 are a plausible bf16 exponent
// (~[117,129]); for f32 data those bits are uniform mantissa bits.
__global__ void inj_flags(const int* eidx, const void* base, int* flags){
  if (threadIdx.x != 0 || blockIdx.x != 0) return;
  int w64 = 1;
  for (int i = 0; i < 64; i++)
    if (eidx[2*i + 1] != 0) w64 = 0;
  flags[0] = w64;
  const inj_u32* b = (const inj_u32*)base;
  int inr = 0;
  for (int i = 0; i < 64; i++){
    inj_u32 ex = (b[i] >> 7) & 0xFFu;
    if (ex >= 100u && ex <= 135u) inr++;
  }
  flags[1] = (inr >= 56) ? 0 : 1;
}

__device__ __forceinline__ int inj_eread(const int* e, size_t i, int w64){
  return w64 ? e[2*i] : e[i];
}

// ---- deg = 1 (self loop) ----
__global__ void inj_initdeg(float* deg){
  int i = blockIdx.x*256 + threadIdx.x;
  if (i < INJ_N) deg[i] = 1.0f;
}

// ---- deg[dst] += 1 over edges ----
__global__ void inj_count(const int* eidx, float* deg, const int* flags){
  int e = blockIdx.x*256 + threadIdx.x;
  int w64 = flags[0];
  if (e < INJ_E) atomicAdd(&deg[inj_eread(eidx, (size_t)INJ_E + e, w64)], 1.0f);
}

// ---- dis = rsqrt(deg) ----
__global__ void inj_dis(const float* deg, float* dis){
  int i = blockIdx.x*256 + threadIdx.x;
  if (i < INJ_N) dis[i] = rsqrtf(deg[i]);
}

// ---- x = relu(ev @ Wp + bp) @ Wg, stored packed bf16 into d_out ----
// 256 threads, 16 nodes/block. Thread (lane,wv): cols 2*lane,2*lane+1; nodes wv+4j.
__global__ void inj_projgcn(const void* ev, const void* Wp, const void* bp,
                            const void* Wg, inj_u32* x, const int* flags){
  __shared__ float s_ev[INJ_NB][INJ_D];
  __shared__ float s_ef[INJ_NB][INJ_H];
  const int f32 = flags[1];
  const int tid = threadIdx.x;
  const int lane = tid & 63, wv = tid >> 6;
  const int n0 = blockIdx.x * INJ_NB;

  for (int i = tid; i < INJ_NB*INJ_D; i += 256)
    s_ev[i>>6][i&63] = inj_ld1(ev, (size_t)(n0 + (i>>6))*INJ_D + (i&63), f32);
  __syncthreads();

  float2 bv = inj_ld2(bp, lane, f32);
  float s0[4], s1[4];
  for (int j=0;j<4;j++){ s0[j]=bv.x; s1[j]=bv.y; }
  for (int k=0;k<INJ_D;k+=4){
    float4 f0 = *(const float4*)&s_ev[wv   ][k];
    float4 f1 = *(const float4*)&s_ev[wv+ 4][k];
    float4 f2 = *(const float4*)&s_ev[wv+ 8][k];
    float4 f3 = *(const float4*)&s_ev[wv+12][k];
    #pragma unroll
    for (int u=0;u<4;u++){
      float2 w = inj_ld2(Wp, (size_t)(k+u)*(INJ_H/2) + lane, f32);
      float e0=((const float*)&f0)[u], e1=((const float*)&f1)[u];
      float e2=((const float*)&f2)[u], e3=((const float*)&f3)[u];
      s0[0]+=e0*w.x; s1[0]+=e0*w.y;
      s0[1]+=e1*w.x; s1[1]+=e1*w.y;
      s0[2]+=e2*w.x; s1[2]+=e2*w.y;
      s0[3]+=e3*w.x; s1[3]+=e3*w.y;
    }
  }
  for (int j=0;j<4;j++){
    int node = wv + 4*j;
    s_ef[node][2*lane  ] = fmaxf(s0[j], 0.f);
    s_ef[node][2*lane+1] = fmaxf(s1[j], 0.f);
  }
  __syncthreads();

  for (int j=0;j<4;j++){ s0[j]=0.f; s1[j]=0.f; }
  for (int k=0;k<INJ_H;k+=4){
    float4 f0 = *(const float4*)&s_ef[wv   ][k];
    float4 f1 = *(const float4*)&s_ef[wv+ 4][k];
    float4 f2 = *(const float4*)&s_ef[wv+ 8][k];
    float4 f3 = *(const float4*)&s_ef[wv+12][k];
    #pragma unroll
    for (int u=0;u<4;u++){
      float2 w = inj_ld2(Wg, (size_t)(k+u)*(INJ_H/2) + lane, f32);
      float e0=((const float*)&f0)[u], e1=((const float*)&f1)[u];
      float e2=((const float*)&f2)[u], e3=((const float*)&f3)[u];
      s0[0]+=e0*w.x; s1[0]+=e0*w.y;
      s0[1]+=e1*w.x; s1[1]+=e1*w.y;
      s0[2]+=e2*w.x; s1[2]+=e2*w.y;
      s0[3]+=e3*w.x; s1[3]+=e3*w.y;
    }
  }
  for (int j=0;j<4;j++){
    int node = n0 + wv + 4*j;
    x[(size_t)node*(INJ_H/2) + lane] =
        ((inj_u32)inj_f2b(s1[j]) << 16) | (inj_u32)inj_f2b(s0[j]);
  }
}

// ---- acc = x * dis^2 (self loop; full write, no pre-zero) ----
__global__ void inj_self(const inj_u32* x, const float* dis, float* acc){
  int t = blockIdx.x*256 + threadIdx.x;   // N*H/2 threads, one u32 pair each
  float d = dis[t >> 6];
  float n = d * d;
  inj_u32 v = x[t];
  float2* a = (float2*)acc;
  float2 o; o.x = inj_b2f((inj_u16)(v & 0xFFFFu)) * n;
  o.y = inj_b2f((inj_u16)(v >> 16)) * n;
  a[t] = o;
}

// ---- acc[dst] += x[src] * dis[src]*dis[dst] : one wave per edge ----
__global__ void inj_scatter(const int* eidx, const inj_u32* x,
                            const float* dis, float* acc, const int* flags){
  int t = blockIdx.x*256 + threadIdx.x;
  int e = t >> 6, lane = t & 63;
  int w64 = flags[0];
  int src = inj_eread(eidx, (size_t)e, w64);
  int dst = inj_eread(eidx, (size_t)INJ_E + e, w64);
  float norm = dis[src] * dis[dst];
  inj_u32 v = x[(size_t)src*(INJ_H/2) + lane];
  float* ar = acc + (size_t)dst*INJ_H + lane*2;
  atomicAdd(ar    , inj_b2f((inj_u16)(v & 0xFFFFu)) * norm);
  atomicAdd(ar + 1, inj_b2f((inj_u16)(v >> 16))     * norm);
}

// ---- gate + fuse epilogue (stub-expected kernel name) ----
__global__ void InjectionLayer_91130616086689_kernel(
    const void* base, const void* b_gcn,
    const void* Wgate, const void* bgate,
    const void* Wfuse, const void* bfuse,
    const float* acc, void* out, const int* flags){
  __shared__ float s_b[INJ_NB][INJ_H];
  __shared__ float s_d[INJ_NB][INJ_H];
  __shared__ float s_c[INJ_NB][INJ_H];
  const int f32 = flags[1];
  const int tid = threadIdx.x;
  const int lane = tid & 63, wv = tid >> 6;
  const int n0 = blockIdx.x * INJ_NB;

  for (int i = tid; i < INJ_NB*INJ_H; i += 256){
    int j = i >> 7, hh = i & 127;
    size_t g = (size_t)(n0 + j)*INJ_H + hh;
    s_b[j][hh] = inj_ld1(base, g, f32);
    s_d[j][hh] = fmaxf(acc[g] + inj_ld1(b_gcn, hh, f32), 0.f);
  }
  __syncthreads();

  // gate = sigmoid([base, diffused] @ Wgate + bgate)
  float2 bv = inj_ld2(bgate, lane, f32);
  float s0[4], s1[4];
  for (int j=0;j<4;j++){ s0[j]=bv.x; s1[j]=bv.y; }
  for (int half=0; half<2; half++){
    const float* feat = (half==0) ? &s_b[0][0] : &s_d[0][0];
    const void* Wb = (const void*)((const char*)Wgate +
        (f32 ? (size_t)half*INJ_H*INJ_H*4 : (size_t)half*INJ_H*INJ_H*2));
    for (int k=0;k<INJ_H;k+=4){
      float4 f0 = *(const float4*)(feat + (wv   )*INJ_H + k);
      float4 f1 = *(const float4*)(feat + (wv+ 4)*INJ_H + k);
      float4 f2 = *(const float4*)(feat + (wv+ 8)*INJ_H + k);
      float4 f3 = *(const float4*)(feat + (wv+12)*INJ_H + k);
      #pragma unroll
      for (int u=0;u<4;u++){
        float2 w = inj_ld2(Wb, (size_t)(k+u)*(INJ_H/2) + lane, f32);
        float e0=((const float*)&f0)[u], e1=((const float*)&f1)[u];
        float e2=((const float*)&f2)[u], e3=((const float*)&f3)[u];
        s0[0]+=e0*w.x; s1[0]+=e0*w.y;
        s0[1]+=e1*w.x; s1[1]+=e1*w.y;
        s0[2]+=e2*w.x; s1[2]+=e2*w.y;
        s0[3]+=e3*w.x; s1[3]+=e3*w.y;
      }
    }
  }
  for (int j=0;j<4;j++){
    int node = wv + 4*j;
    float g0 = 1.f/(1.f + expf(-s0[j]));
    float g1 = 1.f/(1.f + expf(-s1[j]));
    s_c[node][2*lane  ] = s_b[node][2*lane  ]*(1.f-g0) + s_d[node][2*lane  ]*g0;
    s_c[node][2*lane+1] = s_b[node][2*lane+1]*(1.f-g1) + s_d[node][2*lane+1]*g1;
  }
  __syncthreads();

  // out = relu([base, corrected] @ Wfuse + bfuse)
  bv = inj_ld2(bfuse, lane, f32);
  for (int j=0;j<4;j++){ s0[j]=bv.x; s1[j]=bv.y; }
  for (int half=0; half<2; half++){
    const float* feat = (half==0) ? &s_b[0][0] : &s_c[0][0];
    const void* Wb = (const void*)((const char*)Wfuse +
        (f32 ? (size_t)half*INJ_H*INJ_H*4 : (size_t)half*INJ_H*INJ_H*2));
    for (int k=0;k<INJ_H;k+=4){
      float4 f0 = *(const float4*)(feat + (wv   )*INJ_H + k);
      float4 f1 = *(const float4*)(feat + (wv+ 4)*INJ_H + k);
      float4 f2 = *(const float4*)(feat + (wv+ 8)*INJ_H + k);
      float4 f3 = *(const float4*)(feat + (wv+12)*INJ_H + k);
      #pragma unroll
      for (int u=0;u<4;u++){
        float2 w = inj_ld2(Wb, (size_t)(k+u)*(INJ_H/2) + lane, f32);
        float e0=((const float*)&f0)[u], e1=((const float*)&f1)[u];
        float e2=((const float*)&f2)[u], e3=((const float*)&f3)[u];
        s0[0]+=e0*w.x; s1[0]+=e0*w.y;
        s0[1]+=e1*w.x; s1[1]+=e1*w.y;
        s0[2]+=e2*w.x; s1[2]+=e2*w.y;
        s0[3]+=e3*w.x; s1[3]+=e3*w.y;
      }
    }
  }
  for (int j=0;j<4;j++){
    int node = n0 + wv + 4*j;
    inj_st2(out, (size_t)node*(INJ_H/2) + lane,
            fmaxf(s0[j],0.f), fmaxf(s1[j],0.f), f32);
  }
}

extern "C" __attribute__((visibility("default")))
void kernel_launch(void* const* d_in, const int* in_sizes, int n_in,
                   void* d_out, int out_size, void* d_ws, size_t ws_size,
                   hipStream_t stream) {
  const void* base  = d_in[0];
  const void* ev    = d_in[1];
  const int*  eidx  = (const int*)d_in[2];
  const void* Wp    = d_in[3];
  const void* bp    = d_in[4];
  const void* Wg    = d_in[5];
  const void* bg    = d_in[6];
  const void* Wgate = d_in[7];
  const void* bgate = d_in[8];
  const void* Wfuse = d_in[9];
  const void* bfuse = d_in[10];

  // x (packed bf16, 25.6MB) staged in d_out; d_out is >= 25.6MB under both
  // dtype hypotheses and x is dead before the final kernel overwrites it.
  inj_u32* x = (inj_u32*)d_out;

  // workspace layout (52.1 MB)
  char* ws = (char*)d_ws;
  float* acc   = (float*)(ws);               // 51,200,000 B
  float* deg   = (float*)(ws + 51200000);    //    400,000 B
  float* dis   = (float*)(ws + 51600000);    //    400,000 B
  int*   flags = (int*)  (ws + 52000000);    //          8 B

  inj_flags  <<<1, 64, 0, stream>>>(eidx, base, flags);
  inj_initdeg<<<(INJ_N+255)/256, 256, 0, stream>>>(deg);
  inj_count  <<<INJ_E/256, 256, 0, stream>>>(eidx, deg, flags);
  inj_projgcn<<<INJ_N/INJ_NB, 256, 0, stream>>>(ev, Wp, bp, Wg, x, flags);
  inj_dis    <<<(INJ_N+255)/256, 256, 0, stream>>>(deg, dis);
  inj_self   <<<(INJ_N*INJ_H/2)/256, 256, 0, stream>>>(x, dis, acc);
  inj_scatter<<<INJ_E/4, 256, 0, stream>>>(eidx, x, dis, acc, flags);
  InjectionLayer_91130616086689_kernel<<<INJ_N/INJ_NB, 256, 0, stream>>>(
      base, bg, Wgate, bgate, Wfuse, bfuse, acc, d_out, flags);
}

// Round 6
// 1661.968 us; speedup vs baseline: 1.6556x; 1.6556x over previous
//
#include <hip/hip_runtime.h>

// InjectionLayer: event proj + GCNConv diffusion + gated fuse.
// N=100000, E=1600000, EVENT_DIM=64, HID=128.
// R6: CSR-based aggregation replaces 204.8M-atomic scatter (1297us, 1.6GB HBM
// writes). Histogram -> scan -> fill -> per-node wave gather with registers;
// diffused written once as packed bf16 with self-loop/bias/relu fused.
// Runtime-detects edge-index width (int32/int64) and float dtype (f32/bf16).

typedef unsigned short inj_u16;
typedef unsigned int   inj_u32;

static constexpr int INJ_N  = 100000;
static constexpr int INJ_E  = 1600000;
static constexpr int INJ_H  = 128;
static constexpr int INJ_D  = 64;
static constexpr int INJ_NB = 16;    // nodes per block in GEMM kernels
static constexpr int INJ_SB = 391;   // scan blocks = ceil(N/256)

__device__ __forceinline__ float inj_b2f(inj_u16 h){
  union { inj_u32 u; float f; } c; c.u = ((inj_u32)h) << 16; return c.f;
}
__device__ __forceinline__ inj_u16 inj_f2b(float x){
  union { inj_u32 u; float f; } c; c.f = x;
  return (inj_u16)((c.u + 0x7FFFu + ((c.u >> 16) & 1u)) >> 16);
}
__device__ __forceinline__ float inj_lo(inj_u32 w){ return inj_b2f((inj_u16)(w & 0xFFFFu)); }
__device__ __forceinline__ float inj_hi(inj_u32 w){ return inj_b2f((inj_u16)(w >> 16)); }
__device__ __forceinline__ inj_u32 inj_pack(float a, float b){
  return ((inj_u32)inj_f2b(b) << 16) | (inj_u32)inj_f2b(a);
}
// dtype-flexible element access: f32 ? float data : packed bf16 data
__device__ __forceinline__ float inj_ld1(const void* p, size_t i, int f32){
  return f32 ? ((const float*)p)[i] : inj_b2f(((const inj_u16*)p)[i]);
}
__device__ __forceinline__ float2 inj_ld2(const void* p, size_t pair, int f32){
  if (f32) return ((const float2*)p)[pair];
  inj_u32 w = ((const inj_u32*)p)[pair];
  float2 r; r.x = inj_lo(w); r.y = inj_hi(w);
  return r;
}
__device__ __forceinline__ void inj_st2(void* p, size_t pair, float a, float b, int f32){
  if (f32){ float2 v; v.x = a; v.y = b; ((float2*)p)[pair] = v; }
  else ((inj_u32*)p)[pair] = inj_pack(a, b);
}

// ---- runtime format probes (64 threads, ballot-parallel) ----
__global__ void inj_flags(const int* eidx, const inj_u32* base, int* flags){
  int l = threadIdx.x & 63;
  unsigned long long nz = __ballot(eidx[2*l + 1] != 0);
  inj_u32 ex = (base[l] >> 7) & 0xFFu;
  unsigned long long inr = __ballot(ex >= 100u && ex <= 135u);
  if (threadIdx.x == 0){
    flags[0] = (nz == 0ull) ? 1 : 0;              // int64 edges?
    flags[1] = (__popcll(inr) >= 56) ? 0 : 1;     // 0 = bf16, 1 = f32
  }
}

__device__ __forceinline__ int inj_eread(const int* e, size_t i, int w64){
  return w64 ? e[2*i] : e[i];
}

// ---- in-degree histogram (cnt pre-zeroed by hipMemsetAsync) ----
__global__ void inj_hist(const int* eidx, int* cnt, const int* flags){
  int e = blockIdx.x*256 + threadIdx.x;
  int w64 = flags[0];
  if (e < INJ_E) atomicAdd(&cnt[inj_eread(eidx, (size_t)INJ_E + e, w64)], 1);
}

// ---- exclusive scan of cnt -> row_ptr (3 kernels) ----
__global__ void inj_scan1(const int* cnt, int* pre, int* bsum){
  __shared__ int s[256];
  int tid = threadIdx.x, i = blockIdx.x*256 + tid;
  int v = (i < INJ_N) ? cnt[i] : 0;
  s[tid] = v; __syncthreads();
  for (int off = 1; off < 256; off <<= 1){
    int t = (tid >= off) ? s[tid - off] : 0;
    __syncthreads();
    s[tid] += t;
    __syncthreads();
  }
  if (i < INJ_N) pre[i] = s[tid] - v;
  if (tid == 255) bsum[blockIdx.x] = s[255];
}
__global__ void inj_scan2(int* bsum){
  __shared__ int s[512];
  int tid = threadIdx.x;
  int v = (tid < INJ_SB) ? bsum[tid] : 0;
  s[tid] = v; __syncthreads();
  for (int off = 1; off < 512; off <<= 1){
    int t = (tid >= off) ? s[tid - off] : 0;
    __syncthreads();
    s[tid] += t;
    __syncthreads();
  }
  if (tid < INJ_SB) bsum[tid] = s[tid] - v;
}
// pre may alias cursor (same-thread read-then-write of index i).
__global__ void inj_scan3(const int* pre, const int* bsum, const int* cnt,
                          int* row_ptr, int* cursor, float* dis){
  int i = blockIdx.x*256 + threadIdx.x;
  if (i < INJ_N){
    int r = pre[i] + bsum[blockIdx.x];
    row_ptr[i] = r;
    cursor[i]  = r;
    dis[i] = rsqrtf((float)(cnt[i] + 1));   // +1 self loop
  }
  if (i == 0) row_ptr[INJ_N] = INJ_E;
}

// ---- fill CSR edge array (src indices grouped by dst) ----
__global__ void inj_fill(const int* eidx, int* cursor, int* es, const int* flags){
  int e = blockIdx.x*256 + threadIdx.x;
  int w64 = flags[0];
  if (e < INJ_E){
    int src = inj_eread(eidx, (size_t)e, w64);
    int dst = inj_eread(eidx, (size_t)INJ_E + e, w64);
    int pos = atomicAdd(&cursor[dst], 1);
    es[pos] = src;
  }
}

// ---- x = relu(ev @ Wp + bp) @ Wg, stored packed bf16 into d_out ----
__global__ void inj_projgcn(const void* ev, const void* Wp, const void* bp,
                            const void* Wg, inj_u32* x, const int* flags){
  __shared__ float s_ev[INJ_NB][INJ_D];
  __shared__ float s_ef[INJ_NB][INJ_H];
  const int f32 = flags[1];
  const int tid = threadIdx.x;
  const int lane = tid & 63, wv = tid >> 6;
  const int n0 = blockIdx.x * INJ_NB;

  for (int i = tid; i < INJ_NB*INJ_D; i += 256)
    s_ev[i>>6][i&63] = inj_ld1(ev, (size_t)(n0 + (i>>6))*INJ_D + (i&63), f32);
  __syncthreads();

  float2 bv = inj_ld2(bp, lane, f32);
  float s0[4], s1[4];
  for (int j=0;j<4;j++){ s0[j]=bv.x; s1[j]=bv.y; }
  for (int k=0;k<INJ_D;k+=4){
    float4 f0 = *(const float4*)&s_ev[wv   ][k];
    float4 f1 = *(const float4*)&s_ev[wv+ 4][k];
    float4 f2 = *(const float4*)&s_ev[wv+ 8][k];
    float4 f3 = *(const float4*)&s_ev[wv+12][k];
    #pragma unroll
    for (int u=0;u<4;u++){
      float2 w = inj_ld2(Wp, (size_t)(k+u)*(INJ_H/2) + lane, f32);
      float e0=((const float*)&f0)[u], e1=((const float*)&f1)[u];
      float e2=((const float*)&f2)[u], e3=((const float*)&f3)[u];
      s0[0]+=e0*w.x; s1[0]+=e0*w.y;
      s0[1]+=e1*w.x; s1[1]+=e1*w.y;
      s0[2]+=e2*w.x; s1[2]+=e2*w.y;
      s0[3]+=e3*w.x; s1[3]+=e3*w.y;
    }
  }
  for (int j=0;j<4;j++){
    int node = wv + 4*j;
    s_ef[node][2*lane  ] = fmaxf(s0[j], 0.f);
    s_ef[node][2*lane+1] = fmaxf(s1[j], 0.f);
  }
  __syncthreads();

  for (int j=0;j<4;j++){ s0[j]=0.f; s1[j]=0.f; }
  for (int k=0;k<INJ_H;k+=4){
    float4 f0 = *(const float4*)&s_ef[wv   ][k];
    float4 f1 = *(const float4*)&s_ef[wv+ 4][k];
    float4 f2 = *(const float4*)&s_ef[wv+ 8][k];
    float4 f3 = *(const float4*)&s_ef[wv+12][k];
    #pragma unroll
    for (int u=0;u<4;u++){
      float2 w = inj_ld2(Wg, (size_t)(k+u)*(INJ_H/2) + lane, f32);
      float e0=((const float*)&f0)[u], e1=((const float*)&f1)[u];
      float e2=((const float*)&f2)[u], e3=((const float*)&f3)[u];
      s0[0]+=e0*w.x; s1[0]+=e0*w.y;
      s0[1]+=e1*w.x; s1[1]+=e1*w.y;
      s0[2]+=e2*w.x; s1[2]+=e2*w.y;
      s0[3]+=e3*w.x; s1[3]+=e3*w.y;
    }
  }
  for (int j=0;j<4;j++){
    int node = n0 + wv + 4*j;
    x[(size_t)node*(INJ_H/2) + lane] = inj_pack(s0[j], s1[j]);
  }
}

// ---- gather: dif[n] = relu(sum_{e in N(n)} x[src]*dis[src]*dis[n]
//                            + x[n]*dis[n]^2 + b_gcn), packed bf16 ----
// One wave per node, 2 cols/lane; srcs chunked 64-wide, shfl-broadcast.
__global__ void inj_gather(const inj_u32* x, const int* row_ptr, const int* es,
                           const float* dis, const void* b_gcn,
                           inj_u32* dif, const int* flags){
  const int tid = threadIdx.x;
  const int lane = tid & 63, wv = tid >> 6;
  const int n = blockIdx.x*4 + wv;     // grid = N/4 exactly
  const float dd = dis[n];
  inj_u32 xv = x[(size_t)n*64 + lane];
  float a0 = inj_lo(xv)*dd*dd;
  float a1 = inj_hi(xv)*dd*dd;
  const int beg = row_ptr[n], end = row_ptr[n+1];
  for (int c = beg; c < end; c += 64){
    int m = end - c; if (m > 64) m = 64;
    int   src = (lane < m) ? es[c + lane] : 0;
    float ds  = (lane < m) ? dis[src]     : 0.f;
    for (int j = 0; j < m; j++){
      int   sj = __shfl(src, j);
      float nj = __shfl(ds,  j) * dd;
      inj_u32 v = x[(size_t)sj*64 + lane];
      a0 += inj_lo(v)*nj;
      a1 += inj_hi(v)*nj;
    }
  }
  float2 bg = inj_ld2(b_gcn, lane, flags[1]);
  dif[(size_t)n*64 + lane] = inj_pack(fmaxf(a0 + bg.x, 0.f), fmaxf(a1 + bg.y, 0.f));
}

// ---- gate + fuse epilogue ----
__global__ void InjectionLayer_91130616086689_kernel(
    const void* base, const void* Wgate, const void* bgate,
    const void* Wfuse, const void* bfuse,
    const inj_u32* dif, void* out, const int* flags){
  __shared__ float s_b[INJ_NB][INJ_H];
  __shared__ float s_d[INJ_NB][INJ_H];
  __shared__ float s_c[INJ_NB][INJ_H];
  const int f32 = flags[1];
  const int tid = threadIdx.x;
  const int lane = tid & 63, wv = tid >> 6;
  const int n0 = blockIdx.x * INJ_NB;

  for (int i = tid; i < INJ_NB*64; i += 256){
    int j = i >> 6, p = i & 63;
    size_t g = (size_t)(n0 + j)*64 + p;
    float2 bb = inj_ld2(base, g, f32);
    s_b[j][2*p] = bb.x; s_b[j][2*p+1] = bb.y;
    inj_u32 dv = dif[g];
    s_d[j][2*p] = inj_lo(dv); s_d[j][2*p+1] = inj_hi(dv);
  }
  __syncthreads();

  // gate = sigmoid([base, diffused] @ Wgate + bgate)
  float2 bv = inj_ld2(bgate, lane, f32);
  float s0[4], s1[4];
  for (int j=0;j<4;j++){ s0[j]=bv.x; s1[j]=bv.y; }
  for (int half=0; half<2; half++){
    const float* feat = (half==0) ? &s_b[0][0] : &s_d[0][0];
    const void* Wb = (const void*)((const char*)Wgate +
        (f32 ? (size_t)half*INJ_H*INJ_H*4 : (size_t)half*INJ_H*INJ_H*2));
    for (int k=0;k<INJ_H;k+=4){
      float4 f0 = *(const float4*)(feat + (wv   )*INJ_H + k);
      float4 f1 = *(const float4*)(feat + (wv+ 4)*INJ_H + k);
      float4 f2 = *(const float4*)(feat + (wv+ 8)*INJ_H + k);
      float4 f3 = *(const float4*)(feat + (wv+12)*INJ_H + k);
      #pragma unroll
      for (int u=0;u<4;u++){
        float2 w = inj_ld2(Wb, (size_t)(k+u)*(INJ_H/2) + lane, f32);
        float e0=((const float*)&f0)[u], e1=((const float*)&f1)[u];
        float e2=((const float*)&f2)[u], e3=((const float*)&f3)[u];
        s0[0]+=e0*w.x; s1[0]+=e0*w.y;
        s0[1]+=e1*w.x; s1[1]+=e1*w.y;
        s0[2]+=e2*w.x; s1[2]+=e2*w.y;
        s0[3]+=e3*w.x; s1[3]+=e3*w.y;
      }
    }
  }
  for (int j=0;j<4;j++){
    int node = wv + 4*j;
    float g0 = 1.f/(1.f + expf(-s0[j]));
    float g1 = 1.f/(1.f + expf(-s1[j]));
    s_c[node][2*lane  ] = s_b[node][2*lane  ]*(1.f-g0) + s_d[node][2*lane  ]*g0;
    s_c[node][2*lane+1] = s_b[node][2*lane+1]*(1.f-g1) + s_d[node][2*lane+1]*g1;
  }
  __syncthreads();

  // out = relu([base, corrected] @ Wfuse + bfuse)
  bv = inj_ld2(bfuse, lane, f32);
  for (int j=0;j<4;j++){ s0[j]=bv.x; s1[j]=bv.y; }
  for (int half=0; half<2; half++){
    const float* feat = (half==0) ? &s_b[0][0] : &s_c[0][0];
    const void* Wb = (const void*)((const char*)Wfuse +
        (f32 ? (size_t)half*INJ_H*INJ_H*4 : (size_t)half*INJ_H*INJ_H*2));
    for (int k=0;k<INJ_H;k+=4){
      float4 f0 = *(const float4*)(feat + (wv   )*INJ_H + k);
      float4 f1 = *(const float4*)(feat + (wv+ 4)*INJ_H + k);
      float4 f2 = *(const float4*)(feat + (wv+ 8)*INJ_H + k);
      float4 f3 = *(const float4*)(feat + (wv+12)*INJ_H + k);
      #pragma unroll
      for (int u=0;u<4;u++){
        float2 w = inj_ld2(Wb, (size_t)(k+u)*(INJ_H/2) + lane, f32);
        float e0=((const float*)&f0)[u], e1=((const float*)&f1)[u];
        float e2=((const float*)&f2)[u], e3=((const float*)&f3)[u];
        s0[0]+=e0*w.x; s1[0]+=e0*w.y;
        s0[1]+=e1*w.x; s1[1]+=e1*w.y;
        s0[2]+=e2*w.x; s1[2]+=e2*w.y;
        s0[3]+=e3*w.x; s1[3]+=e3*w.y;
      }
    }
  }
  for (int j=0;j<4;j++){
    int node = n0 + wv + 4*j;
    inj_st2(out, (size_t)node*(INJ_H/2) + lane,
            fmaxf(s0[j],0.f), fmaxf(s1[j],0.f), f32);
  }
}

extern "C" __attribute__((visibility("default")))
void kernel_launch(void* const* d_in, const int* in_sizes, int n_in,
                   void* d_out, int out_size, void* d_ws, size_t ws_size,
                   hipStream_t stream) {
  const void* base  = d_in[0];
  const void* ev    = d_in[1];
  const int*  eidx  = (const int*)d_in[2];
  const void* Wp    = d_in[3];
  const void* bp    = d_in[4];
  const void* Wg    = d_in[5];
  const void* bg    = d_in[6];
  const void* Wgate = d_in[7];
  const void* bgate = d_in[8];
  const void* Wfuse = d_in[9];
  const void* bfuse = d_in[10];

  // x (packed bf16, 25.6MB) staged in d_out; dead before final kernel writes.
  inj_u32* x = (inj_u32*)d_out;

  // workspace layout (~33.6 MB)
  char* ws = (char*)d_ws;
  inj_u32* dif    = (inj_u32*)(ws);                 // 25,600,000 B
  int*     es     = (int*)    (ws + 25600000);      //  6,400,000 B
  int*     cnt    = (int*)    (ws + 32000000);      //    400,000 B
  int*     rowp   = (int*)    (ws + 32400000);      //    400,004 B
  int*     cursor = (int*)    (ws + 32800016);      //    400,000 B (aliases pre)
  float*   dis    = (float*)  (ws + 33200016);      //    400,000 B
  int*     bsum   = (int*)    (ws + 33600016);      //      1,564 B
  int*     flags  = (int*)    (ws + 33601600);      //          8 B

  hipMemsetAsync(cnt, 0, (size_t)INJ_N*4, stream);
  inj_flags <<<1, 64, 0, stream>>>(eidx, (const inj_u32*)base, flags);
  inj_hist  <<<INJ_E/256, 256, 0, stream>>>(eidx, cnt, flags);
  inj_projgcn<<<INJ_N/INJ_NB, 256, 0, stream>>>(ev, Wp, bp, Wg, x, flags);
  inj_scan1 <<<INJ_SB, 256, 0, stream>>>(cnt, cursor, bsum);   // pre -> cursor buf
  inj_scan2 <<<1, 512, 0, stream>>>(bsum);
  inj_scan3 <<<INJ_SB, 256, 0, stream>>>(cursor, bsum, cnt, rowp, cursor, dis);
  inj_fill  <<<INJ_E/256, 256, 0, stream>>>(eidx, cursor, es, flags);
  inj_gather<<<INJ_N/4, 256, 0, stream>>>(x, rowp, es, dis, bg, dif, flags);
  InjectionLayer_91130616086689_kernel<<<INJ_N/INJ_NB, 256, 0, stream>>>(
      base, Wgate, bgate, Wfuse, bfuse, dif, d_out, flags);
}

// Round 7
// 1147.068 us; speedup vs baseline: 2.3988x; 1.4489x over previous
//
#include <hip/hip_runtime.h>

// InjectionLayer: event proj + GCNConv diffusion + gated fuse.
// N=100000, E=1600000, EVENT_DIM=64, HID=128.
// R7: all GEMM weights staged in LDS (R6 disease: per-thread global weight
// reads = 886MB fetch, 850us in projgcn). Epilogue = one kernel, two calls
// (gate+blend in-place over dif, then fuse). Gather gets 2-deep prefetch.

typedef unsigned short inj_u16;
typedef unsigned int   inj_u32;

static constexpr int INJ_N  = 100000;
static constexpr int INJ_E  = 1600000;
static constexpr int INJ_H  = 128;
static constexpr int INJ_D  = 64;
static constexpr int INJ_SB = 391;   // scan blocks = ceil(N/256)

__device__ __forceinline__ float inj_b2f(inj_u16 h){
  union { inj_u32 u; float f; } c; c.u = ((inj_u32)h) << 16; return c.f;
}
__device__ __forceinline__ inj_u16 inj_f2b(float x){
  union { inj_u32 u; float f; } c; c.f = x;
  return (inj_u16)((c.u + 0x7FFFu + ((c.u >> 16) & 1u)) >> 16);
}
__device__ __forceinline__ float inj_lo(inj_u32 w){ return inj_b2f((inj_u16)(w & 0xFFFFu)); }
__device__ __forceinline__ float inj_hi(inj_u32 w){ return inj_b2f((inj_u16)(w >> 16)); }
__device__ __forceinline__ inj_u32 inj_pack(float a, float b){
  return ((inj_u32)inj_f2b(b) << 16) | (inj_u32)inj_f2b(a);
}
__device__ __forceinline__ float inj_ld1(const void* p, size_t i, int f32){
  return f32 ? ((const float*)p)[i] : inj_b2f(((const inj_u16*)p)[i]);
}
__device__ __forceinline__ float2 inj_ld2(const void* p, size_t pair, int f32){
  if (f32) return ((const float2*)p)[pair];
  inj_u32 w = ((const inj_u32*)p)[pair];
  float2 r; r.x = inj_lo(w); r.y = inj_hi(w);
  return r;
}
__device__ __forceinline__ void inj_st2(void* p, size_t pair, float a, float b, int f32){
  if (f32){ float2 v; v.x = a; v.y = b; ((float2*)p)[pair] = v; }
  else ((inj_u32*)p)[pair] = inj_pack(a, b);
}
// load one weight pair from global as packed-bf16 u32 (staging only)
__device__ __forceinline__ inj_u32 inj_wpair(const void* p, size_t pair, int f32){
  if (!f32) return ((const inj_u32*)p)[pair];
  float2 v = ((const float2*)p)[pair];
  return inj_pack(v.x, v.y);
}

// ---- runtime format probes ----
__global__ void inj_flags(const int* eidx, const inj_u32* base, int* flags){
  int l = threadIdx.x & 63;
  unsigned long long nz = __ballot(eidx[2*l + 1] != 0);
  inj_u32 ex = (base[l] >> 7) & 0xFFu;
  unsigned long long inr = __ballot(ex >= 100u && ex <= 135u);
  if (threadIdx.x == 0){
    flags[0] = (nz == 0ull) ? 1 : 0;              // int64 edges?
    flags[1] = (__popcll(inr) >= 56) ? 0 : 1;     // 0 = bf16, 1 = f32
  }
}

__device__ __forceinline__ int inj_eread(const int* e, size_t i, int w64){
  return w64 ? e[2*i] : e[i];
}

// ---- in-degree histogram (cnt pre-zeroed) ----
__global__ void inj_hist(const int* eidx, int* cnt, const int* flags){
  int e = blockIdx.x*256 + threadIdx.x;
  int w64 = flags[0];
  if (e < INJ_E) atomicAdd(&cnt[inj_eread(eidx, (size_t)INJ_E + e, w64)], 1);
}

// ---- exclusive scan of cnt -> row_ptr ----
__global__ void inj_scan1(const int* cnt, int* pre, int* bsum){
  __shared__ int s[256];
  int tid = threadIdx.x, i = blockIdx.x*256 + tid;
  int v = (i < INJ_N) ? cnt[i] : 0;
  s[tid] = v; __syncthreads();
  for (int off = 1; off < 256; off <<= 1){
    int t = (tid >= off) ? s[tid - off] : 0;
    __syncthreads();
    s[tid] += t;
    __syncthreads();
  }
  if (i < INJ_N) pre[i] = s[tid] - v;
  if (tid == 255) bsum[blockIdx.x] = s[255];
}
__global__ void inj_scan2(int* bsum){
  __shared__ int s[512];
  int tid = threadIdx.x;
  int v = (tid < INJ_SB) ? bsum[tid] : 0;
  s[tid] = v; __syncthreads();
  for (int off = 1; off < 512; off <<= 1){
    int t = (tid >= off) ? s[tid - off] : 0;
    __syncthreads();
    s[tid] += t;
    __syncthreads();
  }
  if (tid < INJ_SB) bsum[tid] = s[tid] - v;
}
__global__ void inj_scan3(const int* pre, const int* bsum, const int* cnt,
                          int* row_ptr, int* cursor, float* dis){
  int i = blockIdx.x*256 + threadIdx.x;
  if (i < INJ_N){
    int r = pre[i] + bsum[blockIdx.x];
    row_ptr[i] = r;
    cursor[i]  = r;
    dis[i] = rsqrtf((float)(cnt[i] + 1));
  }
  if (i == 0) row_ptr[INJ_N] = INJ_E;
}

// ---- fill CSR edge array ----
__global__ void inj_fill(const int* eidx, int* cursor, int* es, const int* flags){
  int e = blockIdx.x*256 + threadIdx.x;
  int w64 = flags[0];
  if (e < INJ_E){
    int src = inj_eread(eidx, (size_t)e, w64);
    int dst = inj_eread(eidx, (size_t)INJ_E + e, w64);
    int pos = atomicAdd(&cursor[dst], 1);
    es[pos] = src;
  }
}

// ---- x = relu(ev @ Wp + bp) @ Wg  (packed bf16 into d_out) ----
// 16 nodes/block; weights cached in LDS as packed-bf16 u32. LDS = 60KB.
__global__ __launch_bounds__(256) void inj_projgcn(
    const void* ev, const void* Wp, const void* bp, const void* Wg,
    inj_u32* x, const int* flags){
  __shared__ float   s_ev[16][INJ_D];      //  4 KB
  __shared__ float   s_ef[16][INJ_H];      //  8 KB
  __shared__ inj_u32 s_wp[INJ_D][64];      // 16 KB
  __shared__ inj_u32 s_wg[INJ_H][64];      // 32 KB
  const int f32 = flags[1];
  const int tid = threadIdx.x;
  const int lane = tid & 63, wv = tid >> 6;
  const int n0 = blockIdx.x * 16;

  for (int i = tid; i < 16*INJ_D; i += 256)
    s_ev[i>>6][i&63] = inj_ld1(ev, (size_t)(n0 + (i>>6))*INJ_D + (i&63), f32);
  for (int i = tid; i < INJ_D*64; i += 256)
    (&s_wp[0][0])[i] = inj_wpair(Wp, i, f32);
  for (int i = tid; i < INJ_H*64; i += 256)
    (&s_wg[0][0])[i] = inj_wpair(Wg, i, f32);
  __syncthreads();

  float2 bv = inj_ld2(bp, lane, f32);
  float s0[4], s1[4];
  for (int j=0;j<4;j++){ s0[j]=bv.x; s1[j]=bv.y; }
  for (int k=0;k<INJ_D;k+=4){
    float4 f0 = *(const float4*)&s_ev[wv   ][k];
    float4 f1 = *(const float4*)&s_ev[wv+ 4][k];
    float4 f2 = *(const float4*)&s_ev[wv+ 8][k];
    float4 f3 = *(const float4*)&s_ev[wv+12][k];
    #pragma unroll
    for (int u=0;u<4;u++){
      inj_u32 w = s_wp[k+u][lane];
      float wx = inj_lo(w), wy = inj_hi(w);
      float e0=((const float*)&f0)[u], e1=((const float*)&f1)[u];
      float e2=((const float*)&f2)[u], e3=((const float*)&f3)[u];
      s0[0]+=e0*wx; s1[0]+=e0*wy;
      s0[1]+=e1*wx; s1[1]+=e1*wy;
      s0[2]+=e2*wx; s1[2]+=e2*wy;
      s0[3]+=e3*wx; s1[3]+=e3*wy;
    }
  }
  for (int j=0;j<4;j++){
    int node = wv + 4*j;
    s_ef[node][2*lane  ] = fmaxf(s0[j], 0.f);
    s_ef[node][2*lane+1] = fmaxf(s1[j], 0.f);
  }
  __syncthreads();

  for (int j=0;j<4;j++){ s0[j]=0.f; s1[j]=0.f; }
  for (int k=0;k<INJ_H;k+=4){
    float4 f0 = *(const float4*)&s_ef[wv   ][k];
    float4 f1 = *(const float4*)&s_ef[wv+ 4][k];
    float4 f2 = *(const float4*)&s_ef[wv+ 8][k];
    float4 f3 = *(const float4*)&s_ef[wv+12][k];
    #pragma unroll
    for (int u=0;u<4;u++){
      inj_u32 w = s_wg[k+u][lane];
      float wx = inj_lo(w), wy = inj_hi(w);
      float e0=((const float*)&f0)[u], e1=((const float*)&f1)[u];
      float e2=((const float*)&f2)[u], e3=((const float*)&f3)[u];
      s0[0]+=e0*wx; s1[0]+=e0*wy;
      s0[1]+=e1*wx; s1[1]+=e1*wy;
      s0[2]+=e2*wx; s1[2]+=e2*wy;
      s0[3]+=e3*wx; s1[3]+=e3*wy;
    }
  }
  for (int j=0;j<4;j++){
    int node = n0 + wv + 4*j;
    x[(size_t)node*(INJ_H/2) + lane] = inj_pack(s0[j], s1[j]);
  }
}

// ---- gather: dif[n] = relu(sum x[src]*dis[src]*dis[n] + x[n]*dis[n]^2 + b) ----
// One wave per node; 2-deep prefetch of next source row.
__global__ void inj_gather(const inj_u32* x, const int* row_ptr, const int* es,
                           const float* dis, const void* b_gcn,
                           inj_u32* dif, const int* flags){
  const int tid = threadIdx.x;
  const int lane = tid & 63, wv = tid >> 6;
  const int n = blockIdx.x*4 + wv;
  const float dd = dis[n];
  inj_u32 xv = x[(size_t)n*64 + lane];
  float a0 = inj_lo(xv)*dd*dd;
  float a1 = inj_hi(xv)*dd*dd;
  const int beg = row_ptr[n], end = row_ptr[n+1];
  for (int c = beg; c < end; c += 64){
    int m = end - c; if (m > 64) m = 64;
    int   srcv = (lane < m) ? es[c + lane] : 0;
    float dsv  = (lane < m) ? dis[srcv]    : 0.f;
    int sj = __shfl(srcv, 0);
    inj_u32 v = x[(size_t)sj*64 + lane];
    for (int j = 0; j < m; j++){
      float nj = __shfl(dsv, j) * dd;
      inj_u32 vn = v;
      if (j + 1 < m){
        int sn = __shfl(srcv, j + 1);
        vn = x[(size_t)sn*64 + lane];
      }
      a0 += inj_lo(v)*nj;
      a1 += inj_hi(v)*nj;
      v = vn;
    }
  }
  float2 bg = inj_ld2(b_gcn, lane, flags[1]);
  dif[(size_t)n*64 + lane] = inj_pack(fmaxf(a0 + bg.x, 0.f), fmaxf(a1 + bg.y, 0.f));
}

// ---- epilogue GEMM, two modes ----
// mode 0: gate = sigmoid([base,dif]@Wgate+b); corrected = blend -> overwrite dif
// mode 1: out  = relu([base,corrected]@Wfuse+b) -> outp (dtype-flex)
// 16 nodes/block; 2 col-tiles looped inside the block. LDS = 48KB.
__global__ __launch_bounds__(256) void InjectionLayer_91130616086689_kernel(
    const void* base, const void* W, const void* bvec,
    inj_u32* dif, void* outp, const int* flags, int mode){
  __shared__ float   s_feat[16][2*INJ_H];  // 32 KB: [base(128) | dif(128)]
  __shared__ inj_u32 s_w[2*INJ_H][32];     // 32 KB: 256 rows x 32 pairs (one col-tile)
  const int f32 = flags[1];
  const int tid = threadIdx.x;
  const int p = tid & 31, g = tid >> 5;    // pair-in-tile, node-group
  const int n0 = blockIdx.x * 16;

  for (int i = tid; i < 16*128; i += 256){
    int j = i >> 7, q = i & 127;
    float2 v;
    if (q < 64) v = inj_ld2(base, (size_t)(n0 + j)*64 + q, f32);
    else {
      inj_u32 w = dif[(size_t)(n0 + j)*64 + (q - 64)];
      v.x = inj_lo(w); v.y = inj_hi(w);
    }
    s_feat[j][2*q] = v.x; s_feat[j][2*q+1] = v.y;
  }

  for (int ct = 0; ct < 2; ct++){
    __syncthreads();   // feat ready (ct=0); s_w readers done (ct=1)
    for (int i = tid; i < 256*32; i += 256){
      int r = i >> 5, pp = i & 31;
      (&s_w[0][0])[i] = inj_wpair(W, (size_t)r*64 + ct*32 + pp, f32);
    }
    __syncthreads();

    float2 bv = inj_ld2(bvec, ct*32 + p, f32);
    float a0 = bv.x, a1 = bv.y, b0 = bv.x, b1 = bv.y;
    for (int k = 0; k < 2*INJ_H; k += 4){
      float4 fa = *(const float4*)&s_feat[g  ][k];
      float4 fb = *(const float4*)&s_feat[g+8][k];
      #pragma unroll
      for (int u = 0; u < 4; u++){
        inj_u32 w = s_w[k+u][p];
        float wx = inj_lo(w), wy = inj_hi(w);
        float ea = ((const float*)&fa)[u], eb = ((const float*)&fb)[u];
        a0 += ea*wx; a1 += ea*wy;
        b0 += eb*wx; b1 += eb*wy;
      }
    }

    int c0 = ct*64 + 2*p;           // global col of .x
    #pragma unroll
    for (int h = 0; h < 2; h++){
      int   n  = (h==0) ? g : g+8;
      float v0 = (h==0) ? a0 : b0;
      float v1 = (h==0) ? a1 : b1;
      size_t pr = (size_t)(n0 + n)*64 + ct*32 + p;
      if (mode == 0){
        float g0 = 1.f/(1.f + expf(-v0));
        float g1 = 1.f/(1.f + expf(-v1));
        float r0 = s_feat[n][c0  ]*(1.f-g0) + s_feat[n][128+c0  ]*g0;
        float r1 = s_feat[n][c0+1]*(1.f-g1) + s_feat[n][128+c0+1]*g1;
        dif[pr] = inj_pack(r0, r1);
      } else {
        inj_st2(outp, pr, fmaxf(v0, 0.f), fmaxf(v1, 0.f), f32);
      }
    }
  }
}

extern "C" __attribute__((visibility("default")))
void kernel_launch(void* const* d_in, const int* in_sizes, int n_in,
                   void* d_out, int out_size, void* d_ws, size_t ws_size,
                   hipStream_t stream) {
  const void* base  = d_in[0];
  const void* ev    = d_in[1];
  const int*  eidx  = (const int*)d_in[2];
  const void* Wp    = d_in[3];
  const void* bp    = d_in[4];
  const void* Wg    = d_in[5];
  const void* bg    = d_in[6];
  const void* Wgate = d_in[7];
  const void* bgate = d_in[8];
  const void* Wfuse = d_in[9];
  const void* bfuse = d_in[10];

  inj_u32* x = (inj_u32*)d_out;   // staged in d_out; dead before final write

  char* ws = (char*)d_ws;
  inj_u32* dif    = (inj_u32*)(ws);                 // 25,600,000 B (later: corrected, in-place)
  int*     es     = (int*)    (ws + 25600000);      //  6,400,000 B
  int*     cnt    = (int*)    (ws + 32000000);      //    400,000 B
  int*     rowp   = (int*)    (ws + 32400000);      //    400,004 B
  int*     cursor = (int*)    (ws + 32800016);      //    400,000 B
  float*   dis    = (float*)  (ws + 33200016);      //    400,000 B
  int*     bsum   = (int*)    (ws + 33600016);      //      1,564 B
  int*     flags  = (int*)    (ws + 33601600);      //          8 B

  hipMemsetAsync(cnt, 0, (size_t)INJ_N*4, stream);
  inj_flags  <<<1, 64, 0, stream>>>(eidx, (const inj_u32*)base, flags);
  inj_hist   <<<INJ_E/256, 256, 0, stream>>>(eidx, cnt, flags);
  inj_projgcn<<<INJ_N/16, 256, 0, stream>>>(ev, Wp, bp, Wg, x, flags);
  inj_scan1  <<<INJ_SB, 256, 0, stream>>>(cnt, cursor, bsum);
  inj_scan2  <<<1, 512, 0, stream>>>(bsum);
  inj_scan3  <<<INJ_SB, 256, 0, stream>>>(cursor, bsum, cnt, rowp, cursor, dis);
  inj_fill   <<<INJ_E/256, 256, 0, stream>>>(eidx, cursor, es, flags);
  inj_gather <<<INJ_N/4, 256, 0, stream>>>(x, rowp, es, dis, bg, dif, flags);
  InjectionLayer_91130616086689_kernel<<<INJ_N/16, 256, 0, stream>>>(
      base, Wgate, bgate, dif, d_out, flags, 0);
  InjectionLayer_91130616086689_kernel<<<INJ_N/16, 256, 0, stream>>>(
      base, Wfuse, bfuse, dif, d_out, flags, 1);
}

// Round 8
// 709.497 us; speedup vs baseline: 3.8782x; 1.6167x over previous
//
#include <hip/hip_runtime.h>

// InjectionLayer: event proj + GCNConv diffusion + gated fuse.
// N=100000, E=1600000, EVENT_DIM=64, HID=128.
// R8: merged single-launch MFMA epilogue (R7: two VALU-GEMM calls, 580us,
// VALUBusy 52%). Weights pre-repacked to fragment order once (inj_wfrag);
// A-operands staged in LDS fragment order; mfma_f32_16x16x32_bf16.

typedef unsigned short inj_u16;
typedef unsigned int   inj_u32;
typedef __attribute__((ext_vector_type(8))) short bf16x8;
typedef __attribute__((ext_vector_type(4))) float f32x4;

static constexpr int INJ_N  = 100000;
static constexpr int INJ_E  = 1600000;
static constexpr int INJ_H  = 128;
static constexpr int INJ_D  = 64;
static constexpr int INJ_SB = 391;   // scan blocks = ceil(N/256)

__device__ __forceinline__ float inj_b2f(inj_u16 h){
  union { inj_u32 u; float f; } c; c.u = ((inj_u32)h) << 16; return c.f;
}
__device__ __forceinline__ inj_u16 inj_f2b(float x){
  union { inj_u32 u; float f; } c; c.f = x;
  return (inj_u16)((c.u + 0x7FFFu + ((c.u >> 16) & 1u)) >> 16);
}
__device__ __forceinline__ float inj_lo(inj_u32 w){ return inj_b2f((inj_u16)(w & 0xFFFFu)); }
__device__ __forceinline__ float inj_hi(inj_u32 w){ return inj_b2f((inj_u16)(w >> 16)); }
__device__ __forceinline__ inj_u32 inj_pack(float a, float b){
  return ((inj_u32)inj_f2b(b) << 16) | (inj_u32)inj_f2b(a);
}
__device__ __forceinline__ float inj_ld1(const void* p, size_t i, int f32){
  return f32 ? ((const float*)p)[i] : inj_b2f(((const inj_u16*)p)[i]);
}
__device__ __forceinline__ float2 inj_ld2(const void* p, size_t pair, int f32){
  if (f32) return ((const float2*)p)[pair];
  inj_u32 w = ((const inj_u32*)p)[pair];
  float2 r; r.x = inj_lo(w); r.y = inj_hi(w);
  return r;
}
__device__ __forceinline__ inj_u32 inj_wpair(const void* p, size_t pair, int f32){
  if (!f32) return ((const inj_u32*)p)[pair];
  float2 v = ((const float2*)p)[pair];
  return inj_pack(v.x, v.y);
}

// ---- runtime format probes ----
__global__ void inj_flags(const int* eidx, const inj_u32* base, int* flags){
  int l = threadIdx.x & 63;
  unsigned long long nz = __ballot(eidx[2*l + 1] != 0);
  inj_u32 ex = (base[l] >> 7) & 0xFFu;
  unsigned long long inr = __ballot(ex >= 100u && ex <= 135u);
  if (threadIdx.x == 0){
    flags[0] = (nz == 0ull) ? 1 : 0;              // int64 edges?
    flags[1] = (__popcll(inr) >= 56) ? 0 : 1;     // 0 = bf16, 1 = f32
  }
}

__device__ __forceinline__ int inj_eread(const int* e, size_t i, int w64){
  return w64 ? e[2*i] : e[i];
}

// ---- in-degree histogram (cnt pre-zeroed) ----
__global__ void inj_hist(const int* eidx, int* cnt, const int* flags){
  int e = blockIdx.x*256 + threadIdx.x;
  int w64 = flags[0];
  if (e < INJ_E) atomicAdd(&cnt[inj_eread(eidx, (size_t)INJ_E + e, w64)], 1);
}

// ---- exclusive scan of cnt -> row_ptr ----
__global__ void inj_scan1(const int* cnt, int* pre, int* bsum){
  __shared__ int s[256];
  int tid = threadIdx.x, i = blockIdx.x*256 + tid;
  int v = (i < INJ_N) ? cnt[i] : 0;
  s[tid] = v; __syncthreads();
  for (int off = 1; off < 256; off <<= 1){
    int t = (tid >= off) ? s[tid - off] : 0;
    __syncthreads();
    s[tid] += t;
    __syncthreads();
  }
  if (i < INJ_N) pre[i] = s[tid] - v;
  if (tid == 255) bsum[blockIdx.x] = s[255];
}
__global__ void inj_scan2(int* bsum){
  __shared__ int s[512];
  int tid = threadIdx.x;
  int v = (tid < INJ_SB) ? bsum[tid] : 0;
  s[tid] = v; __syncthreads();
  for (int off = 1; off < 512; off <<= 1){
    int t = (tid >= off) ? s[tid - off] : 0;
    __syncthreads();
    s[tid] += t;
    __syncthreads();
  }
  if (tid < INJ_SB) bsum[tid] = s[tid] - v;
}
__global__ void inj_scan3(const int* pre, const int* bsum, const int* cnt,
                          int* row_ptr, int* cursor, float* dis){
  int i = blockIdx.x*256 + threadIdx.x;
  if (i < INJ_N){
    int r = pre[i] + bsum[blockIdx.x];
    row_ptr[i] = r;
    cursor[i]  = r;
    dis[i] = rsqrtf((float)(cnt[i] + 1));
  }
  if (i == 0) row_ptr[INJ_N] = INJ_E;
}

// ---- fill CSR edge array ----
__global__ void inj_fill(const int* eidx, int* cursor, int* es, const int* flags){
  int e = blockIdx.x*256 + threadIdx.x;
  int w64 = flags[0];
  if (e < INJ_E){
    int src = inj_eread(eidx, (size_t)e, w64);
    int dst = inj_eread(eidx, (size_t)INJ_E + e, w64);
    int pos = atomicAdd(&cursor[dst], 1);
    es[pos] = src;
  }
}

// ---- repack Wgate/Wfuse [256][128] into MFMA B-fragment order, bf16 ----
// wfrag[mat][ct][kk][lane][j] = W[kk*32 + (lane>>4)*8 + j][ct*16 + (lane&15)]
__global__ void inj_wfrag(const void* Wgate, const void* Wfuse,
                          inj_u16* wfrag, const int* flags){
  int t = blockIdx.x*256 + threadIdx.x;      // [0, 8192)
  int f32 = flags[1];
  int mat = t >> 12, r = t & 4095;
  int ct = r >> 9, kk = (r >> 6) & 7, lane = r & 63;
  const void* W = mat ? Wfuse : Wgate;
  inj_u16* dst = wfrag + (size_t)mat*32768 + ((ct*8 + kk)*64 + lane)*8;
  int kbase = kk*32 + (lane>>4)*8;
  int n = ct*16 + (lane & 15);
  #pragma unroll
  for (int j=0;j<8;j++)
    dst[j] = inj_f2b(inj_ld1(W, (size_t)(kbase + j)*INJ_H + n, f32));
}

// ---- x = relu(ev @ Wp + bp) @ Wg  (packed bf16 into d_out) ----
// 16 nodes/block; weights cached in LDS as packed-bf16 u32. LDS = 60KB.
__global__ __launch_bounds__(256) void inj_projgcn(
    const void* ev, const void* Wp, const void* bp, const void* Wg,
    inj_u32* x, const int* flags){
  __shared__ float   s_ev[16][INJ_D];
  __shared__ float   s_ef[16][INJ_H];
  __shared__ inj_u32 s_wp[INJ_D][64];
  __shared__ inj_u32 s_wg[INJ_H][64];
  const int f32 = flags[1];
  const int tid = threadIdx.x;
  const int lane = tid & 63, wv = tid >> 6;
  const int n0 = blockIdx.x * 16;

  for (int i = tid; i < 16*INJ_D; i += 256)
    s_ev[i>>6][i&63] = inj_ld1(ev, (size_t)(n0 + (i>>6))*INJ_D + (i&63), f32);
  for (int i = tid; i < INJ_D*64; i += 256)
    (&s_wp[0][0])[i] = inj_wpair(Wp, i, f32);
  for (int i = tid; i < INJ_H*64; i += 256)
    (&s_wg[0][0])[i] = inj_wpair(Wg, i, f32);
  __syncthreads();

  float2 bv = inj_ld2(bp, lane, f32);
  float s0[4], s1[4];
  for (int j=0;j<4;j++){ s0[j]=bv.x; s1[j]=bv.y; }
  for (int k=0;k<INJ_D;k+=4){
    float4 f0 = *(const float4*)&s_ev[wv   ][k];
    float4 f1 = *(const float4*)&s_ev[wv+ 4][k];
    float4 f2 = *(const float4*)&s_ev[wv+ 8][k];
    float4 f3 = *(const float4*)&s_ev[wv+12][k];
    #pragma unroll
    for (int u=0;u<4;u++){
      inj_u32 w = s_wp[k+u][lane];
      float wx = inj_lo(w), wy = inj_hi(w);
      float e0=((const float*)&f0)[u], e1=((const float*)&f1)[u];
      float e2=((const float*)&f2)[u], e3=((const float*)&f3)[u];
      s0[0]+=e0*wx; s1[0]+=e0*wy;
      s0[1]+=e1*wx; s1[1]+=e1*wy;
      s0[2]+=e2*wx; s1[2]+=e2*wy;
      s0[3]+=e3*wx; s1[3]+=e3*wy;
    }
  }
  for (int j=0;j<4;j++){
    int node = wv + 4*j;
    s_ef[node][2*lane  ] = fmaxf(s0[j], 0.f);
    s_ef[node][2*lane+1] = fmaxf(s1[j], 0.f);
  }
  __syncthreads();

  for (int j=0;j<4;j++){ s0[j]=0.f; s1[j]=0.f; }
  for (int k=0;k<INJ_H;k+=4){
    float4 f0 = *(const float4*)&s_ef[wv   ][k];
    float4 f1 = *(const float4*)&s_ef[wv+ 4][k];
    float4 f2 = *(const float4*)&s_ef[wv+ 8][k];
    float4 f3 = *(const float4*)&s_ef[wv+12][k];
    #pragma unroll
    for (int u=0;u<4;u++){
      inj_u32 w = s_wg[k+u][lane];
      float wx = inj_lo(w), wy = inj_hi(w);
      float e0=((const float*)&f0)[u], e1=((const float*)&f1)[u];
      float e2=((const float*)&f2)[u], e3=((const float*)&f3)[u];
      s0[0]+=e0*wx; s1[0]+=e0*wy;
      s0[1]+=e1*wx; s1[1]+=e1*wy;
      s0[2]+=e2*wx; s1[2]+=e2*wy;
      s0[3]+=e3*wx; s1[3]+=e3*wy;
    }
  }
  for (int j=0;j<4;j++){
    int node = n0 + wv + 4*j;
    x[(size_t)node*(INJ_H/2) + lane] = inj_pack(s0[j], s1[j]);
  }
}

// ---- gather: dif[n] = relu(sum x[src]*dis[src]*dis[n] + x[n]*dis[n]^2 + b) ----
__global__ void inj_gather(const inj_u32* x, const int* row_ptr, const int* es,
                           const float* dis, const void* b_gcn,
                           inj_u32* dif, const int* flags){
  const int tid = threadIdx.x;
  const int lane = tid & 63, wv = tid >> 6;
  const int n = blockIdx.x*4 + wv;
  const float dd = dis[n];
  inj_u32 xv = x[(size_t)n*64 + lane];
  float a0 = inj_lo(xv)*dd*dd;
  float a1 = inj_hi(xv)*dd*dd;
  const int beg = row_ptr[n], end = row_ptr[n+1];
  for (int c = beg; c < end; c += 64){
    int m = end - c; if (m > 64) m = 64;
    int   srcv = (lane < m) ? es[c + lane] : 0;
    float dsv  = (lane < m) ? dis[srcv]    : 0.f;
    int sj = __shfl(srcv, 0);
    inj_u32 v = x[(size_t)sj*64 + lane];
    for (int j = 0; j < m; j++){
      float nj = __shfl(dsv, j) * dd;
      inj_u32 vn = v;
      if (j + 1 < m){
        int sn = __shfl(srcv, j + 1);
        vn = x[(size_t)sn*64 + lane];
      }
      a0 += inj_lo(v)*nj;
      a1 += inj_hi(v)*nj;
      v = vn;
    }
  }
  float2 bg = inj_ld2(b_gcn, lane, flags[1]);
  dif[(size_t)n*64 + lane] = inj_pack(fmaxf(a0 + bg.x, 0.f), fmaxf(a1 + bg.y, 0.f));
}

// ---- merged MFMA epilogue: gate -> blend -> fuse -> out, one launch ----
// 16 nodes/block, 4 waves; wave w covers cols [32w, 32w+32) (2 col-tiles).
// A-operands in LDS fragment order: elem(m, k) at [g*136 + m*8 + (k&7)],
// g = (k>>5)*4 + ((k>>3)&3)  (uniform LDS banks for b128 frag reads).
__global__ __launch_bounds__(256) void InjectionLayer_91130616086689_kernel(
    const void* base, const void* bgate, const void* bfuse,
    const inj_u16* wgf, const inj_u16* wff,
    const inj_u32* dif, void* outp, const int* flags){
  __shared__ __align__(16) inj_u16 s_b[16*136];   // base  frags (4352 B)
  __shared__ __align__(16) inj_u16 s_d[16*136];   // dif   frags
  __shared__ __align__(16) inj_u16 s_c[16*136];   // corrected frags
  const int f32 = flags[1];
  const int tid = threadIdx.x;
  const int n0 = blockIdx.x * 16;

  // ---- stage base + dif into fragment-order LDS ----
  {
    int m = tid >> 4, g = tid & 15;               // node, 8-col group
    uint4 vb;
    if (!f32){
      vb = ((const uint4*)base)[(size_t)(n0 + m)*16 + g];
    } else {
      const float4* b4 = (const float4*)base;
      float4 x0 = b4[(size_t)(n0 + m)*32 + g*2];
      float4 x1 = b4[(size_t)(n0 + m)*32 + g*2 + 1];
      vb.x = inj_pack(x0.x, x0.y); vb.y = inj_pack(x0.z, x0.w);
      vb.z = inj_pack(x1.x, x1.y); vb.w = inj_pack(x1.z, x1.w);
    }
    *(uint4*)(s_b + g*136 + m*8) = vb;
    uint4 vd = ((const uint4*)dif)[(size_t)(n0 + m)*16 + g];
    *(uint4*)(s_d + g*136 + m*8) = vd;
  }
  __syncthreads();

  const int lane = tid & 63, wave = tid >> 6;
  const int mrow = lane & 15, quad = lane >> 4;

  // ---- GEMM1: gate_pre = [base|dif] @ Wgate ----
  f32x4 accg[2] = {{0.f,0.f,0.f,0.f},{0.f,0.f,0.f,0.f}};
  #pragma unroll
  for (int kk = 0; kk < 8; kk++){
    const inj_u16* mat = (kk < 4) ? s_b : s_d;
    int g = (kk & 3)*4 + quad;
    bf16x8 a = *(const bf16x8*)(mat + g*136 + mrow*8);
    bf16x8 b0 = *(const bf16x8*)(wgf + (((wave*2    )*8 + kk)*64 + lane)*8);
    bf16x8 b1 = *(const bf16x8*)(wgf + (((wave*2 + 1)*8 + kk)*64 + lane)*8);
    accg[0] = __builtin_amdgcn_mfma_f32_16x16x32_bf16(a, b0, accg[0], 0, 0, 0);
    accg[1] = __builtin_amdgcn_mfma_f32_16x16x32_bf16(a, b1, accg[1], 0, 0, 0);
  }

  // ---- sigmoid + blend -> corrected frags ----
  #pragma unroll
  for (int t = 0; t < 2; t++){
    int col = (wave*2 + t)*16 + mrow;
    float bg = inj_ld1(bgate, col, f32);
    int gk = (col >> 5)*4 + ((col >> 3) & 3), jj = col & 7;
    #pragma unroll
    for (int r = 0; r < 4; r++){
      int row = quad*4 + r;
      float gate = 1.f/(1.f + expf(-(accg[t][r] + bg)));
      int off = gk*136 + row*8 + jj;
      float bb = inj_b2f(s_b[off]);
      float dd = inj_b2f(s_d[off]);
      s_c[off] = inj_f2b(bb*(1.f - gate) + dd*gate);
    }
  }
  __syncthreads();

  // ---- GEMM2: out = relu([base|corrected] @ Wfuse + b) ----
  f32x4 accf[2] = {{0.f,0.f,0.f,0.f},{0.f,0.f,0.f,0.f}};
  #pragma unroll
  for (int kk = 0; kk < 8; kk++){
    const inj_u16* mat = (kk < 4) ? s_b : s_c;
    int g = (kk & 3)*4 + quad;
    bf16x8 a = *(const bf16x8*)(mat + g*136 + mrow*8);
    bf16x8 b0 = *(const bf16x8*)(wff + (((wave*2    )*8 + kk)*64 + lane)*8);
    bf16x8 b1 = *(const bf16x8*)(wff + (((wave*2 + 1)*8 + kk)*64 + lane)*8);
    accf[0] = __builtin_amdgcn_mfma_f32_16x16x32_bf16(a, b0, accf[0], 0, 0, 0);
    accf[1] = __builtin_amdgcn_mfma_f32_16x16x32_bf16(a, b1, accf[1], 0, 0, 0);
  }
  #pragma unroll
  for (int t = 0; t < 2; t++){
    int col = (wave*2 + t)*16 + mrow;
    float bf = inj_ld1(bfuse, col, f32);
    #pragma unroll
    for (int r = 0; r < 4; r++){
      int row = quad*4 + r;
      float v = fmaxf(accf[t][r] + bf, 0.f);
      size_t oi = (size_t)(n0 + row)*INJ_H + col;
      if (f32) ((float*)outp)[oi] = v;
      else     ((inj_u16*)outp)[oi] = inj_f2b(v);
    }
  }
}

extern "C" __attribute__((visibility("default")))
void kernel_launch(void* const* d_in, const int* in_sizes, int n_in,
                   void* d_out, int out_size, void* d_ws, size_t ws_size,
                   hipStream_t stream) {
  const void* base  = d_in[0];
  const void* ev    = d_in[1];
  const int*  eidx  = (const int*)d_in[2];
  const void* Wp    = d_in[3];
  const void* bp    = d_in[4];
  const void* Wg    = d_in[5];
  const void* bg    = d_in[6];
  const void* Wgate = d_in[7];
  const void* bgate = d_in[8];
  const void* Wfuse = d_in[9];
  const void* bfuse = d_in[10];

  inj_u32* x = (inj_u32*)d_out;   // staged in d_out; dead before final write

  char* ws = (char*)d_ws;
  inj_u32* dif    = (inj_u32*)(ws);                 // 25,600,000 B
  int*     es     = (int*)    (ws + 25600000);      //  6,400,000 B
  int*     cnt    = (int*)    (ws + 32000000);      //    400,000 B
  int*     rowp   = (int*)    (ws + 32400000);      //    400,004 B
  int*     cursor = (int*)    (ws + 32800016);      //    400,000 B
  float*   dis    = (float*)  (ws + 33200016);      //    400,000 B
  int*     bsum   = (int*)    (ws + 33600016);      //      1,564 B
  int*     flags  = (int*)    (ws + 33601600);      //          8 B
  inj_u16* wfrag  = (inj_u16*)(ws + 33601664);      //    131,072 B (wgf|wff)

  hipMemsetAsync(cnt, 0, (size_t)INJ_N*4, stream);
  inj_flags  <<<1, 64, 0, stream>>>(eidx, (const inj_u32*)base, flags);
  inj_hist   <<<INJ_E/256, 256, 0, stream>>>(eidx, cnt, flags);
  inj_wfrag  <<<32, 256, 0, stream>>>(Wgate, Wfuse, wfrag, flags);
  inj_projgcn<<<INJ_N/16, 256, 0, stream>>>(ev, Wp, bp, Wg, x, flags);
  inj_scan1  <<<INJ_SB, 256, 0, stream>>>(cnt, cursor, bsum);
  inj_scan2  <<<1, 512, 0, stream>>>(bsum);
  inj_scan3  <<<INJ_SB, 256, 0, stream>>>(cursor, bsum, cnt, rowp, cursor, dis);
  inj_fill   <<<INJ_E/256, 256, 0, stream>>>(eidx, cursor, es, flags);
  inj_gather <<<INJ_N/4, 256, 0, stream>>>(x, rowp, es, dis, bg, dif, flags);
  InjectionLayer_91130616086689_kernel<<<INJ_N/16, 256, 0, stream>>>(
      base, bgate, bfuse, wfrag, wfrag + 32768, dif, d_out, flags);
}